// Round 8
// baseline (355.498 us; speedup 1.0000x reference)
//
#include <hip/hip_runtime.h>
#include <hip/hip_bf16.h>

// Problem: B=4, S=2048, D=1024, H=16, E=64
#define B_ 4
#define S_ 2048
#define D_ 1024
#define H_ 16
#define E_ 64
#define M_ (B_*S_)      // 8192 rows
#define NQKV_ 3072

typedef __attribute__((ext_vector_type(8))) short bf16x8;
typedef __attribute__((ext_vector_type(4))) float f32x4;
typedef __attribute__((ext_vector_type(4))) unsigned short u16x4;
typedef unsigned short u16;

#define QSCALE 0.18033688011f   // log2(e)/8: folded into Q at GEMM epilogue

static __device__ __forceinline__ u16 f2bf(float f) {
  unsigned u = __builtin_bit_cast(unsigned, f);
  unsigned r = (u + 0x7FFFu + ((u >> 16) & 1u)) >> 16;
  return (u16)r;
}

// packed RNE f32x2 -> bf16x2 (low = a, high = b)
static __device__ __forceinline__ unsigned pk2(float a, float b) {
  unsigned r;
  asm("v_cvt_pk_bf16_f32 %0, %1, %2" : "=v"(r) : "v"(a), "v"(b));
  return r;
}

// ---------------- conversion kernels ----------------

__global__ __launch_bounds__(256) void cvt4(const float* __restrict__ in,
                                            u16* __restrict__ out, int n4) {
  int i = blockIdx.x * 256 + threadIdx.x;
  if (i >= n4) return;
  f32x4 v = ((const f32x4*)in)[i];
  u16x4 o;
  o.x = f2bf(v.x); o.y = f2bf(v.y); o.z = f2bf(v.z); o.w = f2bf(v.w);
  ((u16x4*)out)[i] = o;
}

// Wq/Wk/Wv [H,D,E] -> Wt [3072][1024] (Wt[n][k] = W[k][n]) via LDS transpose.
// Block = one (h, 64-wide d-slice); coalesced reads AND writes (old version
// did 3M uncoalesced 2B scatter stores).
__global__ __launch_bounds__(256) void cvt_wqkv(const float* __restrict__ Wq,
                                                const float* __restrict__ Wk,
                                                const float* __restrict__ Wv,
                                                u16* __restrict__ Wt) {
  __shared__ float t[64][65];
  const int h = blockIdx.x >> 4;
  const int db = (blockIdx.x & 15) * 64;
  const int tid = threadIdx.x;
  const float* srcs[3] = {Wq, Wk, Wv};
#pragma unroll
  for (int m = 0; m < 3; ++m) {
    const float* src = srcs[m] + (size_t)h * 65536 + (size_t)db * 64;
    __syncthreads();
#pragma unroll
    for (int i = 0; i < 16; ++i) {
      int idx = i * 256 + tid;
      int d = idx >> 6, e = idx & 63;
      t[e][d] = src[d * 64 + e];           // consecutive tid -> consecutive e
    }
    __syncthreads();
    u16* dst = Wt + (size_t)(m * 1024 + h * 64) * 1024 + db;
#pragma unroll
    for (int i = 0; i < 16; ++i) {
      int idx = i * 256 + tid;
      int e = idx >> 6, d = idx & 63;
      dst[(size_t)e * 1024 + d] = f2bf(t[e][d]);  // consecutive tid -> consecutive d
    }
  }
}

// ---------------- GEMM: C[M,N] = A[M,K] * Bt[N,K]^T ----------------
// 128x128 tile, BK=32, 4 waves (2x2 of 64x64), global_load_lds w=16.
// QKV instance (Vt!=null): bn<8 (Q cols) pre-scaled by QSCALE; bn>=16
// (V cols) written TRANSPOSED into Vt[(b*1024 + (c-2048))*2048 + s].

template<bool FP32OUT>
__global__ __launch_bounds__(256) void gemm_bt(const u16* __restrict__ A,
                                               const u16* __restrict__ Bt,
                                               void* __restrict__ Cv, int ldC,
                                               u16* __restrict__ Vt,
                                               const float* __restrict__ bias,
                                               int M, int N, int K) {
  __shared__ u16 As[128 * 32];
  __shared__ u16 Bs[128 * 32];
  const int tid = threadIdx.x;
  const int lane = tid & 63, wid = tid >> 6;
  const int bm = blockIdx.x, bn = blockIdx.y;
  const int wr = wid >> 1, wc = wid & 1;
  const int ll = lane & 15, lg = lane >> 4;

  f32x4 acc[4][4] = {};

  const int srow = lane >> 2;          // row within 16-row chunk
  const int scol = (lane & 3) * 8;     // element col within BK=32

  for (int k0 = 0; k0 < K; k0 += 32) {
#pragma unroll
    for (int p = 0; p < 2; ++p) {
      int row = p * 64 + wid * 16 + srow;
      const u16* ga = A + (size_t)(bm * 128 + row) * K + k0 + scol;
      __builtin_amdgcn_global_load_lds(
          (const __attribute__((address_space(1))) void*)ga,
          (__attribute__((address_space(3))) void*)(As + p * 2048 + wid * 512),
          16, 0, 0);
      const u16* gb = Bt + (size_t)(bn * 128 + row) * K + k0 + scol;
      __builtin_amdgcn_global_load_lds(
          (const __attribute__((address_space(1))) void*)gb,
          (__attribute__((address_space(3))) void*)(Bs + p * 2048 + wid * 512),
          16, 0, 0);
    }
    __syncthreads();
    bf16x8 af[4], bfr[4];
#pragma unroll
    for (int mi = 0; mi < 4; ++mi)
      af[mi] = *(const bf16x8*)&As[(wr * 64 + mi * 16 + ll) * 32 + lg * 8];
#pragma unroll
    for (int ni = 0; ni < 4; ++ni)
      bfr[ni] = *(const bf16x8*)&Bs[(wc * 64 + ni * 16 + ll) * 32 + lg * 8];
#pragma unroll
    for (int mi = 0; mi < 4; ++mi)
#pragma unroll
      for (int ni = 0; ni < 4; ++ni)
        acc[mi][ni] = __builtin_amdgcn_mfma_f32_16x16x32_bf16(af[mi], bfr[ni],
                                                              acc[mi][ni], 0, 0, 0);
    __syncthreads();
  }

  // epilogue: C/D layout col = lane&15, row = (lane>>4)*4 + reg
  const int crow0 = bm * 128 + wr * 64;
  const int ccol0 = bn * 128 + wc * 64 + ll;
  const bool vblk = (Vt != nullptr) && (bn >= 16);   // uniform per block
  const float qs = (Vt != nullptr && bn < 8) ? QSCALE : 1.0f;
#pragma unroll
  for (int mi = 0; mi < 4; ++mi) {
#pragma unroll
    for (int ni = 0; ni < 4; ++ni) {
      int c = ccol0 + ni * 16;
      if (vblk) {
        int r0 = crow0 + mi * 16 + lg * 4;       // token of j=0 (mult of 4)
        int bb = r0 >> 11, s0 = r0 & 2047;
        u16x4 pkv;
        pkv.x = f2bf(acc[mi][ni][0]); pkv.y = f2bf(acc[mi][ni][1]);
        pkv.z = f2bf(acc[mi][ni][2]); pkv.w = f2bf(acc[mi][ni][3]);
        *(u16x4*)&Vt[((size_t)(bb * 1024 + (c - 2048))) * 2048 + s0] = pkv;
      } else {
#pragma unroll
        for (int j = 0; j < 4; ++j) {
          int r = crow0 + mi * 16 + lg * 4 + j;
          if (FP32OUT) {
            ((float*)Cv)[(size_t)r * ldC + c] = acc[mi][ni][j] + bias[c];
          } else {
            ((u16*)Cv)[(size_t)r * ldC + c] = f2bf(acc[mi][ni][j] * qs);
          }
        }
      }
    }
  }
}

// ------- flash attention (causal), swapped-QK^T, NO-LDS / NO-BARRIER -------
// Grid: 1024 flat blocks, 256 thr = 4 waves x 16 q-rows, QBLK=64, KVBLK=64.
// Block pr handles q-tiles {pr, 31-pr} sequentially: 33 k-tiles, balanced.
// Waves are fully independent: K/V fragments load straight from global
// (L1/L2-hot; XCD remap keeps each XCD's K/V slice in its own L2).
// No __syncthreads anywhere -> compiler pipelines tile t+1 loads under
// tile t softmax (the overlap a barrier's vmcnt(0) drain prevents).
// kappa(nt, r) = 32*(nt>>1) + 8*(r>>2) + 4*(nt&1) + (r&3); key of s[nt][j]
// at lane lg = kb + 32*(nt>>1) + lg*8 + 4*(nt&1) + j.  (verified R5/R7)
// Defer-max (T13) with per-lane trigger: __any(pm_lane - m_run > 8); the
// cross-lane max reduce happens only inside the rare rescale branch.

__global__ __launch_bounds__(256, 4) void attn(const u16* __restrict__ QK,
                                               const u16* __restrict__ Vt,
                                               u16* __restrict__ AO) {
  // XCD-chunked remap: XCD x hosts bh in [x*8, x*8+8)
  const int wg = blockIdx.x;                 // 0..1023
  const int lin = (wg & 7) * 128 + (wg >> 3);
  const int bh = lin >> 4, pr = lin & 15;
  const int b = bh >> 4, h = bh & 15;
  const int lane = threadIdx.x & 63, wid = threadIdx.x >> 6;
  const int ll = lane & 15, lg = lane >> 4;

  // per-lane fragment base pointers (tile 0); K rows are kappa-permuted
  const u16* kp[4];
#pragma unroll
  for (int nt = 0; nt < 4; ++nt) {
    int krow = 32 * (nt >> 1) + ((ll >> 2) << 3) + ((nt & 1) << 2) + (ll & 3);
    kp[nt] = QK + (size_t)(b * S_ + krow) * 2048 + 1024 + h * E_ + lg * 8;
  }
  const u16* vp[4];
#pragma unroll
  for (int ent = 0; ent < 4; ++ent)
    vp[ent] = Vt + (size_t)(bh * 64 + ent * 16 + ll) * 2048 + lg * 8;

  for (int ph = 0; ph < 2; ++ph) {
    const int qt = ph ? 31 - pr : pr;
    const int nkt = qt + 1;
    const int q = qt * 64 + wid * 16 + ll;

    // Q fragments (B-operand, pre-scaled): col = ll (q-row), k = e chunk lg*8
    const u16* qp = QK + (size_t)(b * S_ + q) * 2048 + h * E_;
    bf16x8 qf0 = *(const bf16x8*)(qp + lg * 8);
    bf16x8 qf1 = *(const bf16x8*)(qp + 32 + lg * 8);

    float m_run = -INFINITY;         // running max (exp2 domain)
    float l_part = 0.f;              // per-lane partial sum
    f32x4 o_acc[4] = {};

    for (int kt = 0; kt < nkt; ++kt) {
      const size_t ka = (size_t)kt * (64 * 2048);   // +64 K-rows (elements)
      const size_t va = (size_t)kt * 64;            // +64 V-cols (elements)

      // S^T = mfma(K, Q): lane -> q-row ll, 16 keys across (nt, j)
      f32x4 s[4] = {};
      __builtin_amdgcn_s_setprio(1);
#pragma unroll
      for (int ks = 0; ks < 2; ++ks) {
        bf16x8 qf = ks ? qf1 : qf0;
#pragma unroll
        for (int nt = 0; nt < 4; ++nt) {
          bf16x8 kf = *(const bf16x8*)(kp[nt] + ka + ks * 32);
          s[nt] = __builtin_amdgcn_mfma_f32_16x16x32_bf16(kf, qf, s[nt], 0, 0, 0);
        }
      }
      __builtin_amdgcn_s_setprio(0);

      // causal mask (diag tile only); S already scaled (Q pre-scaled)
      if (kt == qt) {
        const int kb = kt * 64;
#pragma unroll
        for (int nt = 0; nt < 4; ++nt) {
          int keyb = kb + 32 * (nt >> 1) + 4 * (nt & 1) + lg * 8;
#pragma unroll
          for (int j = 0; j < 4; ++j)
            if (keyb + j > q) s[nt][j] = -1e30f;
        }
      }

      // T13 defer-max, per-lane trigger (no cross-lane on the fast path)
      float pm = -3.0e38f;
#pragma unroll
      for (int nt = 0; nt < 4; ++nt)
#pragma unroll
        for (int j = 0; j < 4; ++j) pm = fmaxf(pm, s[nt][j]);
      if (__any(pm - m_run > 8.0f)) {          // rare after first tile
        float g = fmaxf(pm, __shfl_xor(pm, 16, 64));
        g = fmaxf(g, __shfl_xor(g, 32, 64));   // group (q-row) max
        float mn = fmaxf(m_run, g);
        float corr = exp2f(m_run - mn);        // 0 on first tile (m=-inf)
        m_run = mn;
        l_part *= corr;
#pragma unroll
        for (int ent = 0; ent < 4; ++ent)
#pragma unroll
          for (int j = 0; j < 4; ++j) o_acc[ent][j] *= corr;
      }

      // fused exp2 -> pack -> PV  (p <= 2^8 guaranteed)
      __builtin_amdgcn_s_setprio(1);
#pragma unroll
      for (int ks = 0; ks < 2; ++ks) {
        float p0 = exp2f(s[2 * ks][0] - m_run);
        float p1 = exp2f(s[2 * ks][1] - m_run);
        float p2 = exp2f(s[2 * ks][2] - m_run);
        float p3 = exp2f(s[2 * ks][3] - m_run);
        float p4_ = exp2f(s[2 * ks + 1][0] - m_run);
        float p5 = exp2f(s[2 * ks + 1][1] - m_run);
        float p6 = exp2f(s[2 * ks + 1][2] - m_run);
        float p7 = exp2f(s[2 * ks + 1][3] - m_run);
        l_part += ((p0 + p1) + (p2 + p3)) + ((p4_ + p5) + (p6 + p7));
        union { unsigned w[4]; bf16x8 v; } pf;
        pf.w[0] = pk2(p0, p1);
        pf.w[1] = pk2(p2, p3);
        pf.w[2] = pk2(p4_, p5);
        pf.w[3] = pk2(p6, p7);
#pragma unroll
        for (int ent = 0; ent < 4; ++ent) {
          bf16x8 vf = *(const bf16x8*)(vp[ent] + va + ks * 32);
          o_acc[ent] = __builtin_amdgcn_mfma_f32_16x16x32_bf16(
              vf, pf.v, o_acc[ent], 0, 0, 0);
        }
      }
      __builtin_amdgcn_s_setprio(0);
    }

    // single cross-lane l reduce (lanes sharing ll hold same q-row)
    float l_run = l_part;
    l_run += __shfl_xor(l_run, 16, 64);
    l_run += __shfl_xor(l_run, 32, 64);
    float rl = 1.0f / l_run;

    // epilogue: O^T[e = ent*16+lg*4+j][q = ll]; AO write u16x4 along j
#pragma unroll
    for (int ent = 0; ent < 4; ++ent) {
      u16x4 o;
#pragma unroll
      for (int j = 0; j < 4; ++j) o[j] = f2bf(o_acc[ent][j] * rl);
      *(u16x4*)&AO[(size_t)(b * S_ + q) * D_ + h * E_ + ent * 16 + lg * 4] = o;
    }
  }
}

// ---------------- launcher ----------------

extern "C" void kernel_launch(void* const* d_in, const int* in_sizes, int n_in,
                              void* d_out, int out_size, void* d_ws, size_t ws_size,
                              hipStream_t stream) {
  const float* embedded = (const float*)d_in[0];
  const float* Wq = (const float*)d_in[1];
  const float* Wk = (const float*)d_in[2];
  const float* Wv = (const float*)d_in[3];
  const float* Wo = (const float*)d_in[4];
  const float* bo = (const float*)d_in[5];
  float* out = (float*)d_out;

  char* ws = (char*)d_ws;
  u16* X    = (u16*)(ws);                     // [8192][1024]  16 MiB @ 0
  u16* Wqkv = (u16*)(ws + (16u << 20));       // [3072][1024]   6 MiB @ 16M
  u16* WoT  = (u16*)(ws + (22u << 20));       // [1024][1024]   2 MiB @ 22M
  u16* QK   = (u16*)(ws + (24u << 20));       // [8192][2048]  32 MiB @ 24M
  u16* Vt   = (u16*)(ws + (56u << 20));       // [64][64][2048] 16 MiB @ 56M
  u16* AO   = (u16*)(ws + (72u << 20));       // [8192][1024]  16 MiB @ 72M

  // 1) embedded fp32 -> bf16
  cvt4<<<8192, 256, 0, stream>>>(embedded, X, 2097152);
  // 2) W_qkv repack+cast (LDS-transpose, coalesced both sides)
  cvt_wqkv<<<256, 256, 0, stream>>>(Wq, Wk, Wv, Wqkv);
  // 3) Wo cast
  cvt4<<<1024, 256, 0, stream>>>(Wo, WoT, 262144);
  // 4) QKV projection: QK normal (stride 2048, Q pre-scaled), V -> Vt
  gemm_bt<false><<<dim3(64, 24), 256, 0, stream>>>(X, Wqkv, QK, 2048, Vt,
                                                   nullptr, M_, NQKV_, 1024);
  // 5) causal flash attention (no-LDS, no-barrier, folded-pair grid)
  attn<<<1024, 256, 0, stream>>>(QK, Vt, AO);
  // 6) output projection + bias -> fp32 d_out
  gemm_bt<true><<<dim3(64, 8), 256, 0, stream>>>(AO, WoT, out, 1024, nullptr,
                                                 bo, M_, 1024, 1024);
}

// Round 9
// 187.714 us; speedup vs baseline: 1.8938x; 1.8938x over previous
//
#include <hip/hip_runtime.h>
#include <hip/hip_bf16.h>

// Problem: B=4, S=2048, D=1024, H=16, E=64
#define B_ 4
#define S_ 2048
#define D_ 1024
#define H_ 16
#define E_ 64
#define M_ (B_*S_)      // 8192 rows
#define NQKV_ 3072

typedef __attribute__((ext_vector_type(8))) short bf16x8;
typedef __attribute__((ext_vector_type(4))) float f32x4;
typedef __attribute__((ext_vector_type(16))) float f32x16;
typedef __attribute__((ext_vector_type(4))) unsigned short u16x4;
typedef unsigned short u16;

#define QSCALE 0.18033688011f   // log2(e)/8: folded into Q at GEMM epilogue
#define AS1 __attribute__((address_space(1)))
#define AS3 __attribute__((address_space(3)))

static __device__ __forceinline__ u16 f2bf(float f) {
  unsigned u = __builtin_bit_cast(unsigned, f);
  unsigned r = (u + 0x7FFFu + ((u >> 16) & 1u)) >> 16;
  return (u16)r;
}

// packed RNE f32x2 -> bf16x2 (low = a, high = b)
static __device__ __forceinline__ unsigned pk2(float a, float b) {
  unsigned r;
  asm("v_cvt_pk_bf16_f32 %0, %1, %2" : "=v"(r) : "v"(a), "v"(b));
  return r;
}

// ---------------- conversion kernels ----------------

__global__ __launch_bounds__(256) void cvt4(const float* __restrict__ in,
                                            u16* __restrict__ out, int n4) {
  int i = blockIdx.x * 256 + threadIdx.x;
  if (i >= n4) return;
  f32x4 v = ((const f32x4*)in)[i];
  u16x4 o;
  o.x = f2bf(v.x); o.y = f2bf(v.y); o.z = f2bf(v.z); o.w = f2bf(v.w);
  ((u16x4*)out)[i] = o;
}

// Wq/Wk/Wv [H,D,E] -> Wt [3072][1024] (Wt[n][k] = W[k][n]) via LDS transpose.
__global__ __launch_bounds__(256) void cvt_wqkv(const float* __restrict__ Wq,
                                                const float* __restrict__ Wk,
                                                const float* __restrict__ Wv,
                                                u16* __restrict__ Wt) {
  __shared__ float t[64][65];
  const int h = blockIdx.x >> 4;
  const int db = (blockIdx.x & 15) * 64;
  const int tid = threadIdx.x;
  const float* srcs[3] = {Wq, Wk, Wv};
#pragma unroll
  for (int m = 0; m < 3; ++m) {
    const float* src = srcs[m] + (size_t)h * 65536 + (size_t)db * 64;
    __syncthreads();
#pragma unroll
    for (int i = 0; i < 16; ++i) {
      int idx = i * 256 + tid;
      int d = idx >> 6, e = idx & 63;
      t[e][d] = src[d * 64 + e];
    }
    __syncthreads();
    u16* dst = Wt + (size_t)(m * 1024 + h * 64) * 1024 + db;
#pragma unroll
    for (int i = 0; i < 16; ++i) {
      int idx = i * 256 + tid;
      int e = idx >> 6, d = idx & 63;
      dst[(size_t)e * 1024 + d] = f2bf(t[e][d]);
    }
  }
}

// ---------------- GEMM: C[M,N] = A[M,K] * Bt[N,K]^T ----------------
// 128x128 tile, BK=32, 4 waves (2x2 of 64x64), global_load_lds w=16.
// QKV instance (Vt!=null): bn<8 (Q cols) pre-scaled by QSCALE; bn>=16
// (V cols) written TRANSPOSED into Vt with sigma-permuted token position:
// within each 16-token group, 4-token blocks 1 and 2 swap. This makes the
// attn PV B-operand (P registers) pair with V k-slots with NO cross-lane
// moves at 32x32 MFMA (slot t holds key 4*(t>>3)+(t&3)+8*((t>>2)&1)).

template<bool FP32OUT>
__global__ __launch_bounds__(256) void gemm_bt(const u16* __restrict__ A,
                                               const u16* __restrict__ Bt,
                                               void* __restrict__ Cv, int ldC,
                                               u16* __restrict__ Vt,
                                               const float* __restrict__ bias,
                                               int M, int N, int K) {
  __shared__ u16 As[128 * 32];
  __shared__ u16 Bs[128 * 32];
  const int tid = threadIdx.x;
  const int lane = tid & 63, wid = tid >> 6;
  const int bm = blockIdx.x, bn = blockIdx.y;
  const int wr = wid >> 1, wc = wid & 1;
  const int ll = lane & 15, lg = lane >> 4;

  f32x4 acc[4][4] = {};

  const int srow = lane >> 2;
  const int scol = (lane & 3) * 8;

  for (int k0 = 0; k0 < K; k0 += 32) {
#pragma unroll
    for (int p = 0; p < 2; ++p) {
      int row = p * 64 + wid * 16 + srow;
      const u16* ga = A + (size_t)(bm * 128 + row) * K + k0 + scol;
      __builtin_amdgcn_global_load_lds(
          (const AS1 void*)ga, (AS3 void*)(As + p * 2048 + wid * 512), 16, 0, 0);
      const u16* gb = Bt + (size_t)(bn * 128 + row) * K + k0 + scol;
      __builtin_amdgcn_global_load_lds(
          (const AS1 void*)gb, (AS3 void*)(Bs + p * 2048 + wid * 512), 16, 0, 0);
    }
    __syncthreads();
    bf16x8 af[4], bfr[4];
#pragma unroll
    for (int mi = 0; mi < 4; ++mi)
      af[mi] = *(const bf16x8*)&As[(wr * 64 + mi * 16 + ll) * 32 + lg * 8];
#pragma unroll
    for (int ni = 0; ni < 4; ++ni)
      bfr[ni] = *(const bf16x8*)&Bs[(wc * 64 + ni * 16 + ll) * 32 + lg * 8];
#pragma unroll
    for (int mi = 0; mi < 4; ++mi)
#pragma unroll
      for (int ni = 0; ni < 4; ++ni)
        acc[mi][ni] = __builtin_amdgcn_mfma_f32_16x16x32_bf16(af[mi], bfr[ni],
                                                              acc[mi][ni], 0, 0, 0);
    __syncthreads();
  }

  const int crow0 = bm * 128 + wr * 64;
  const int ccol0 = bn * 128 + wc * 64 + ll;
  const bool vblk = (Vt != nullptr) && (bn >= 16);
  const float qs = (Vt != nullptr && bn < 8) ? QSCALE : 1.0f;
  const int sig = (((lg & 1) << 1) | (lg >> 1)) << 2;   // sigma on 4-blocks
#pragma unroll
  for (int mi = 0; mi < 4; ++mi) {
#pragma unroll
    for (int ni = 0; ni < 4; ++ni) {
      int c = ccol0 + ni * 16;
      if (vblk) {
        int r0 = crow0 + mi * 16 + lg * 4;       // token of j=0 (mult of 4)
        int bb = r0 >> 11, s0 = r0 & 2047;
        int s0p = (s0 & ~15) | sig;              // sigma-permuted position
        u16x4 pkv;
        pkv.x = f2bf(acc[mi][ni][0]); pkv.y = f2bf(acc[mi][ni][1]);
        pkv.z = f2bf(acc[mi][ni][2]); pkv.w = f2bf(acc[mi][ni][3]);
        *(u16x4*)&Vt[((size_t)(bb * 1024 + (c - 2048))) * 2048 + s0p] = pkv;
      } else {
#pragma unroll
        for (int j = 0; j < 4; ++j) {
          int r = crow0 + mi * 16 + lg * 4 + j;
          if (FP32OUT) {
            ((float*)Cv)[(size_t)r * ldC + c] = acc[mi][ni][j] + bias[c];
          } else {
            ((u16*)Cv)[(size_t)r * ldC + c] = f2bf(acc[mi][ni][j] * qs);
          }
        }
      }
    }
  }
}

// ------- flash attention (causal): 8-wave, QBLK=256, 32x32 MFMA -----------
// Grid: 256 blocks x 512 thr (8 waves x 32 q-rows). Block pr handles q-tiles
// {pr, 7-pr} of 256 rows: 36 KVBLK=64 tiles total, perfectly balanced.
// Swapped QK^T at 32x32x16: A=K (row=lane&31=key, k=(lane>>5)*8+j = e),
// B=Q (col=lane&31=q, same k map). C layout (HW-verified): col=lane&31=q,
// row(key) = (r&3)+8*(r>>2)+4*(lane>>5), r=0..15. PV: A=V^T (row=e), with
// sigma-permuted V columns so B=P uses s-registers in sequential pairs.
// 4-buffer LDS ring + counted vmcnt(4): stage t+1,t+2 stay in flight across
// the single per-tile barrier (T4). Defer-max (T13). exp2-domain (Q presc).

#define SWZ(r) ((((r) & 7) ^ ((((r) >> 3) & 3) << 1)) << 4)

__global__ __launch_bounds__(512, 2) void attn(const u16* __restrict__ QK,
                                               const u16* __restrict__ Vt,
                                               u16* __restrict__ AO) {
  __shared__ u16 Klds[4][4096];      // ring of [key 0..63][e 0..63], swizzled
  __shared__ u16 Vlds[4][4096];      // ring of V^T [e][key-slot], swizzled

  // XCD-chunked remap: XCD x hosts bh in [x*8, x*8+8)
  const int wg = blockIdx.x;                 // 0..255
  const int lin = (wg & 7) * 32 + (wg >> 3);
  const int bh = lin >> 2, pr = lin & 3;
  const int b = bh >> 4, h = bh & 15;
  const int tid = threadIdx.x;
  const int lane = tid & 63, wv = tid >> 6;  // 8 waves
  const int lq = lane & 31, hi = lane >> 5;

  // staging source (tile 0), inverse-swizzled; dest is wave-uniform base
  const int srow = tid >> 3;                 // 0..63
  const int scolb = ((tid & 7) * 16) ^ SWZ(srow);
  const char* ksrc = (const char*)(QK + (size_t)(b * S_ + srow) * 2048 + 1024 + h * E_) + scolb;
  const char* vsrc = (const char*)(Vt + (size_t)(bh * 64 + srow) * 2048) + scolb;

  const int nktA = 4 * pr + 4;
  const int NS = 36;

  auto stage = [&](int sq, int kb) {
    char* kd = (char*)&Klds[0][0] + (sq & 3) * 8192 + wv * 1024;
    char* vd = (char*)&Vlds[0][0] + (sq & 3) * 8192 + wv * 1024;
    __builtin_amdgcn_global_load_lds((const AS1 void*)(ksrc + (size_t)kb * 4096),
                                     (AS3 void*)kd, 16, 0, 0);
    __builtin_amdgcn_global_load_lds((const AS1 void*)(vsrc + kb * 2),
                                     (AS3 void*)vd, 16, 0, 0);
  };

  stage(0, 0);
  stage(1, (1 < nktA ? 1 : 1 - nktA) * 64);

  int seq = 0;
  for (int ph = 0; ph < 2; ++ph) {
    const int qt = ph ? 7 - pr : pr;
    const int nkt = 4 * qt + 4;
    const int qw0 = qt * 256 + wv * 32;
    const int q = qw0 + lq;

    // Q fragments (B-operand, pre-scaled): col=q, k-slot e = c*16 + hi*8 + j
    const u16* qp = QK + (size_t)(b * S_ + q) * 2048 + h * E_;
    bf16x8 qf[4];
#pragma unroll
    for (int c = 0; c < 4; ++c)
      qf[c] = *(const bf16x8*)(qp + c * 16 + hi * 8);

    float m_run = -INFINITY, l_part = 0.f;
    f32x16 o0 = {}, o1 = {};

    for (int kt = 0; kt < nkt; ++kt, ++seq) {
      if (seq + 2 < NS) {
        int s2 = seq + 2;
        stage(s2, (s2 < nktA ? s2 : s2 - nktA) * 64);
      }
      if (seq < NS - 2)       asm volatile("s_waitcnt vmcnt(4)" ::: "memory");
      else if (seq == NS - 2) asm volatile("s_waitcnt vmcnt(2)" ::: "memory");
      else                    asm volatile("s_waitcnt vmcnt(0)" ::: "memory");
      __builtin_amdgcn_s_barrier();

      const int kb = kt * 64;
      if (kb > qw0 + 31) continue;         // fully masked for this wave
      const char* kbuf = (const char*)&Klds[0][0] + (seq & 3) * 8192;
      const char* vbuf = (const char*)&Vlds[0][0] + (seq & 3) * 8192;

      auto half = [&](int kb2) __attribute__((always_inline)) {
        // S^T (32 keys x 32 q): acc over 4 e-chunks
        f32x16 sc = {};
        __builtin_amdgcn_s_setprio(1);
        const int krow = kb2 * 32 + lq;
#pragma unroll
        for (int c = 0; c < 4; ++c) {
          bf16x8 kf = *(const bf16x8*)(kbuf + krow * 128 +
                                       ((c * 32 + hi * 16) ^ SWZ(krow)));
          sc = __builtin_amdgcn_mfma_f32_32x32x16_bf16(kf, qf[c], sc, 0, 0, 0);
        }
        __builtin_amdgcn_s_setprio(0);

        // causal mask (boundary halves only)
        if (kb + kb2 * 32 + 31 > qw0) {
#pragma unroll
          for (int r = 0; r < 16; ++r) {
            int key = kb + kb2 * 32 + (r & 3) + 8 * (r >> 2) + 4 * hi;
            if (key > q) sc[r] = -1e30f;
          }
        }

        // T13 defer-max (per-lane trigger; pair-reduce only when rescaling)
        float pm = sc[0];
#pragma unroll
        for (int r = 1; r < 16; ++r) pm = fmaxf(pm, sc[r]);
        if (__any(pm - m_run > 8.0f)) {
          float g = fmaxf(pm, __shfl_xor(pm, 32, 64));
          float mn = fmaxf(m_run, g);
          float corr = exp2f(m_run - mn);
          m_run = mn;
          l_part *= corr;
          o0 *= corr;
          o1 *= corr;
        }

        // exp2 -> pack (sequential pairs!) -> PV
        float p[16];
#pragma unroll
        for (int r = 0; r < 16; ++r) {
          p[r] = exp2f(sc[r] - m_run);
          l_part += p[r];
        }
        __builtin_amdgcn_s_setprio(1);
#pragma unroll
        for (int gg = 0; gg < 2; ++gg) {
          union { unsigned w[4]; bf16x8 v; } pf;
          pf.w[0] = pk2(p[gg * 8 + 0], p[gg * 8 + 1]);
          pf.w[1] = pk2(p[gg * 8 + 2], p[gg * 8 + 3]);
          pf.w[2] = pk2(p[gg * 8 + 4], p[gg * 8 + 5]);
          pf.w[3] = pk2(p[gg * 8 + 6], p[gg * 8 + 7]);
          const int g = kb2 * 2 + gg;
          {
            bf16x8 vf = *(const bf16x8*)(vbuf + lq * 128 +
                                         ((g * 32 + hi * 16) ^ SWZ(lq)));
            o0 = __builtin_amdgcn_mfma_f32_32x32x16_bf16(vf, pf.v, o0, 0, 0, 0);
          }
          {
            const int er = 32 + lq;
            bf16x8 vf = *(const bf16x8*)(vbuf + er * 128 +
                                         ((g * 32 + hi * 16) ^ SWZ(er)));
            o1 = __builtin_amdgcn_mfma_f32_32x32x16_bf16(vf, pf.v, o1, 0, 0, 0);
          }
        }
        __builtin_amdgcn_s_setprio(0);
      };

      half(0);
      if (kb + 32 <= qw0 + 31) half(1);
    }

    // final l reduce: lanes lq and lq+32 hold same q, disjoint keys
    float l = l_part + __shfl_xor(l_part, 32, 64);
    float rl = 1.0f / l;

    // epilogue: e = eb*32 + 8*qd + 4*hi + j, q = col
#pragma unroll
    for (int qd = 0; qd < 4; ++qd) {
      u16x4 w0, w1;
#pragma unroll
      for (int j = 0; j < 4; ++j) {
        w0[j] = f2bf(o0[qd * 4 + j] * rl);
        w1[j] = f2bf(o1[qd * 4 + j] * rl);
      }
      const size_t base = (size_t)(b * S_ + q) * D_ + h * E_ + 8 * qd + 4 * hi;
      *(u16x4*)&AO[base] = w0;
      *(u16x4*)&AO[base + 32] = w1;
    }
  }
}

// ---------------- launcher ----------------

extern "C" void kernel_launch(void* const* d_in, const int* in_sizes, int n_in,
                              void* d_out, int out_size, void* d_ws, size_t ws_size,
                              hipStream_t stream) {
  const float* embedded = (const float*)d_in[0];
  const float* Wq = (const float*)d_in[1];
  const float* Wk = (const float*)d_in[2];
  const float* Wv = (const float*)d_in[3];
  const float* Wo = (const float*)d_in[4];
  const float* bo = (const float*)d_in[5];
  float* out = (float*)d_out;

  char* ws = (char*)d_ws;
  u16* X    = (u16*)(ws);                     // [8192][1024]  16 MiB @ 0
  u16* Wqkv = (u16*)(ws + (16u << 20));       // [3072][1024]   6 MiB @ 16M
  u16* WoT  = (u16*)(ws + (22u << 20));       // [1024][1024]   2 MiB @ 22M
  u16* QK   = (u16*)(ws + (24u << 20));       // [8192][2048]  32 MiB @ 24M
  u16* Vt   = (u16*)(ws + (56u << 20));       // [64][64][2048] 16 MiB @ 56M
  u16* AO   = (u16*)(ws + (72u << 20));       // [8192][1024]  16 MiB @ 72M

  // 1) embedded fp32 -> bf16
  cvt4<<<8192, 256, 0, stream>>>(embedded, X, 2097152);
  // 2) W_qkv repack+cast (LDS-transpose, coalesced both sides)
  cvt_wqkv<<<256, 256, 0, stream>>>(Wq, Wk, Wv, Wqkv);
  // 3) Wo cast
  cvt4<<<1024, 256, 0, stream>>>(Wo, WoT, 262144);
  // 4) QKV projection: QK (Q pre-scaled), V -> sigma-permuted Vt
  gemm_bt<false><<<dim3(64, 24), 256, 0, stream>>>(X, Wqkv, QK, 2048, Vt,
                                                   nullptr, M_, NQKV_, 1024);
  // 5) causal flash attention (8-wave, 32x32, counted-vmcnt ring)
  attn<<<256, 512, 0, stream>>>(QK, Vt, AO);
  // 6) output projection + bias -> fp32 d_out
  gemm_bt<true><<<dim3(64, 8), 256, 0, stream>>>(AO, WoT, out, 1024, nullptr,
                                                 bo, M_, 1024, 1024);
}

// Round 10
// 179.872 us; speedup vs baseline: 1.9764x; 1.0436x over previous
//
#include <hip/hip_runtime.h>
#include <hip/hip_bf16.h>

// Problem: B=4, S=2048, D=1024, H=16, E=64
#define B_ 4
#define S_ 2048
#define D_ 1024
#define H_ 16
#define E_ 64
#define M_ (B_*S_)      // 8192 rows
#define NQKV_ 3072

typedef __attribute__((ext_vector_type(8))) short bf16x8;
typedef __attribute__((ext_vector_type(4))) float f32x4;
typedef __attribute__((ext_vector_type(16))) float f32x16;
typedef __attribute__((ext_vector_type(4))) unsigned short u16x4;
typedef unsigned short u16;

#define QSCALE 0.18033688011f   // log2(e)/8: folded into Q at GEMM epilogue
#define AS1 __attribute__((address_space(1)))
#define AS3 __attribute__((address_space(3)))

// XOR swizzle on 16B slots within a 128B row (session-verified: 0 conflicts)
#define SWZ(r) ((((r) & 7) ^ ((((r) >> 3) & 3) << 1)) << 4)

static __device__ __forceinline__ u16 f2bf(float f) {
  unsigned u = __builtin_bit_cast(unsigned, f);
  unsigned r = (u + 0x7FFFu + ((u >> 16) & 1u)) >> 16;
  return (u16)r;
}

// packed RNE f32x2 -> bf16x2 (low = a, high = b)
static __device__ __forceinline__ unsigned pk2(float a, float b) {
  unsigned r;
  asm("v_cvt_pk_bf16_f32 %0, %1, %2" : "=v"(r) : "v"(a), "v"(b));
  return r;
}

// ---------------- conversion kernels ----------------

__global__ __launch_bounds__(256) void cvt4(const float* __restrict__ in,
                                            u16* __restrict__ out, int n4) {
  int i = blockIdx.x * 256 + threadIdx.x;
  if (i >= n4) return;
  f32x4 v = ((const f32x4*)in)[i];
  u16x4 o;
  o.x = f2bf(v.x); o.y = f2bf(v.y); o.z = f2bf(v.z); o.w = f2bf(v.w);
  ((u16x4*)out)[i] = o;
}

// Wq/Wk/Wv [H,D,E] -> Wt [3072][1024] (Wt[n][k] = W[k][n]) via LDS transpose.
__global__ __launch_bounds__(256) void cvt_wqkv(const float* __restrict__ Wq,
                                                const float* __restrict__ Wk,
                                                const float* __restrict__ Wv,
                                                u16* __restrict__ Wt) {
  __shared__ float t[64][65];
  const int h = blockIdx.x >> 4;
  const int db = (blockIdx.x & 15) * 64;
  const int tid = threadIdx.x;
  const float* srcs[3] = {Wq, Wk, Wv};
#pragma unroll
  for (int m = 0; m < 3; ++m) {
    const float* src = srcs[m] + (size_t)h * 65536 + (size_t)db * 64;
    __syncthreads();
#pragma unroll
    for (int i = 0; i < 16; ++i) {
      int idx = i * 256 + tid;
      int d = idx >> 6, e = idx & 63;
      t[e][d] = src[d * 64 + e];
    }
    __syncthreads();
    u16* dst = Wt + (size_t)(m * 1024 + h * 64) * 1024 + db;
#pragma unroll
    for (int i = 0; i < 16; ++i) {
      int idx = i * 256 + tid;
      int e = idx >> 6, d = idx & 63;
      dst[(size_t)e * 1024 + d] = f2bf(t[e][d]);
    }
  }
}

// -------- QKV GEMM: deep-pipelined 256x192 tile, BK=64, counted vmcnt ------
// C[8192,3072] = X[8192,1024] * Wqkv[3072,1024]^T.
// 8 waves (2M x 4N), per-wave 128x48 output: acc[8][3], 48 MFMA + 22
// ds_read_b128 per K-tile per wave (3x the MFMA-per-barrier of the m97 loop).
// Double-buffered LDS (112 KB), stage-1-ahead with OWN-wave counted
// s_waitcnt vmcnt(7) -> s_barrier -> compute -> s_barrier (R9-attn-verified
// mechanics; vmcnt never drains to 0 in the steady loop).  T2 swizzle via
// inverse-swizzled global_load_lds source (linear LDS dest, rule 21).
// Epilogue: per-16-col fragment region flags: c<1024 Q (pre-scaled QSCALE),
// c<2048 K, c>=2048 V -> transposed sigma-permuted Vt (verified formula).

__global__ __launch_bounds__(512, 1) void gemm_qkv(const u16* __restrict__ A,
                                                   const u16* __restrict__ Bt,
                                                   u16* __restrict__ QK,
                                                   u16* __restrict__ Vt) {
  __shared__ u16 As[2][256 * 64];    // 32 KB per buffer
  __shared__ u16 Bs[2][192 * 64];    // 24 KB per buffer
  const int tid = threadIdx.x;
  const int lane = tid & 63, wv = tid >> 6;
  const int ll = lane & 15, lg = lane >> 4;
  const int wm = wv >> 2, wn = wv & 3;       // 2 x 4 wave grid
  const int bm = blockIdx.x, bn = blockIdx.y;

  // staging sources (K-tile 0), inverse-swizzled cols; LDS dest is linear
  const int sr = tid >> 3;                   // row-sub 0..63
  const int scb = (tid & 7) * 16;            // 16B slot byte
  const char* asrc[4];
  const char* bsrc[3];
#pragma unroll
  for (int i = 0; i < 4; ++i) {
    int row = i * 64 + sr;
    asrc[i] = (const char*)(A + (size_t)(bm * 256 + row) * 1024) + (scb ^ SWZ(row));
  }
#pragma unroll
  for (int i = 0; i < 3; ++i) {
    int row = i * 64 + sr;
    bsrc[i] = (const char*)(Bt + (size_t)(bn * 192 + row) * 1024) + (scb ^ SWZ(row));
  }

  auto stage = [&](int t) {
    const size_t adv = (size_t)t * 128;      // BK=64 elems * 2B
    char* ad = (char*)&As[t & 1][0] + tid * 16;
    char* bd = (char*)&Bs[t & 1][0] + tid * 16;
#pragma unroll
    for (int i = 0; i < 4; ++i)
      __builtin_amdgcn_global_load_lds((const AS1 void*)(asrc[i] + adv),
                                       (AS3 void*)(ad + i * 8192), 16, 0, 0);
#pragma unroll
    for (int i = 0; i < 3; ++i)
      __builtin_amdgcn_global_load_lds((const AS1 void*)(bsrc[i] + adv),
                                       (AS3 void*)(bd + i * 8192), 16, 0, 0);
  };

  f32x4 acc[8][3] = {};

  stage(0);
  for (int t = 0; t < 16; ++t) {
    if (t + 1 < 16) stage(t + 1);
    if (t < 15) asm volatile("s_waitcnt vmcnt(7)" ::: "memory");
    else        asm volatile("s_waitcnt vmcnt(0)" ::: "memory");
    __builtin_amdgcn_s_barrier();

    const char* ab = (const char*)&As[t & 1][0];
    const char* bb = (const char*)&Bs[t & 1][0];

    bf16x8 bf_[3][2];
#pragma unroll
    for (int ni = 0; ni < 3; ++ni) {
      int row = wn * 48 + ni * 16 + ll;
#pragma unroll
      for (int ks = 0; ks < 2; ++ks)
        bf_[ni][ks] = *(const bf16x8*)(bb + row * 128 +
                                       ((ks * 64 + lg * 16) ^ SWZ(row)));
    }
    __builtin_amdgcn_s_setprio(1);
#pragma unroll
    for (int mi = 0; mi < 8; ++mi) {
      int row = wm * 128 + mi * 16 + ll;
#pragma unroll
      for (int ks = 0; ks < 2; ++ks) {
        bf16x8 af = *(const bf16x8*)(ab + row * 128 +
                                     ((ks * 64 + lg * 16) ^ SWZ(row)));
#pragma unroll
        for (int ni = 0; ni < 3; ++ni)
          acc[mi][ni] = __builtin_amdgcn_mfma_f32_16x16x32_bf16(
              af, bf_[ni][ks], acc[mi][ni], 0, 0, 0);
      }
    }
    __builtin_amdgcn_s_setprio(0);
    __builtin_amdgcn_s_barrier();
  }

  // epilogue (per-fragment region: Q scaled / K plain / V -> sigma Vt)
  const int sig = (((lg & 1) << 1) | (lg >> 1)) << 2;   // sigma on 4-blocks
#pragma unroll
  for (int mi = 0; mi < 8; ++mi) {
#pragma unroll
    for (int ni = 0; ni < 3; ++ni) {
      int c = bn * 192 + wn * 48 + ni * 16 + ll;
      int r0 = bm * 256 + wm * 128 + mi * 16 + lg * 4;   // token of j=0
      if (c >= 2048) {                                   // V region
        int bb2 = r0 >> 11, s0 = r0 & 2047;
        int s0p = (s0 & ~15) | sig;
        u16x4 pkv;
        pkv.x = f2bf(acc[mi][ni][0]); pkv.y = f2bf(acc[mi][ni][1]);
        pkv.z = f2bf(acc[mi][ni][2]); pkv.w = f2bf(acc[mi][ni][3]);
        *(u16x4*)&Vt[((size_t)(bb2 * 1024 + (c - 2048))) * 2048 + s0p] = pkv;
      } else {
        const float qs = (c < 1024) ? QSCALE : 1.0f;
#pragma unroll
        for (int j = 0; j < 4; ++j)
          QK[(size_t)(r0 + j) * 2048 + c] = f2bf(acc[mi][ni][j] * qs);
      }
    }
  }
}

// ---------------- GEMM: C[M,N] = A[M,K] * Bt[N,K]^T (out-proj) ------------
// 128x128 tile, BK=32, 4 waves (2x2 of 64x64), global_load_lds w=16.

template<bool FP32OUT>
__global__ __launch_bounds__(256) void gemm_bt(const u16* __restrict__ A,
                                               const u16* __restrict__ Bt,
                                               void* __restrict__ Cv, int ldC,
                                               u16* __restrict__ Vt,
                                               const float* __restrict__ bias,
                                               int M, int N, int K) {
  __shared__ u16 As[128 * 32];
  __shared__ u16 Bs[128 * 32];
  const int tid = threadIdx.x;
  const int lane = tid & 63, wid = tid >> 6;
  const int bm = blockIdx.x, bn = blockIdx.y;
  const int wr = wid >> 1, wc = wid & 1;
  const int ll = lane & 15, lg = lane >> 4;

  f32x4 acc[4][4] = {};

  const int srow = lane >> 2;
  const int scol = (lane & 3) * 8;

  for (int k0 = 0; k0 < K; k0 += 32) {
#pragma unroll
    for (int p = 0; p < 2; ++p) {
      int row = p * 64 + wid * 16 + srow;
      const u16* ga = A + (size_t)(bm * 128 + row) * K + k0 + scol;
      __builtin_amdgcn_global_load_lds(
          (const AS1 void*)ga, (AS3 void*)(As + p * 2048 + wid * 512), 16, 0, 0);
      const u16* gb = Bt + (size_t)(bn * 128 + row) * K + k0 + scol;
      __builtin_amdgcn_global_load_lds(
          (const AS1 void*)gb, (AS3 void*)(Bs + p * 2048 + wid * 512), 16, 0, 0);
    }
    __syncthreads();
    bf16x8 af[4], bfr[4];
#pragma unroll
    for (int mi = 0; mi < 4; ++mi)
      af[mi] = *(const bf16x8*)&As[(wr * 64 + mi * 16 + ll) * 32 + lg * 8];
#pragma unroll
    for (int ni = 0; ni < 4; ++ni)
      bfr[ni] = *(const bf16x8*)&Bs[(wc * 64 + ni * 16 + ll) * 32 + lg * 8];
#pragma unroll
    for (int mi = 0; mi < 4; ++mi)
#pragma unroll
      for (int ni = 0; ni < 4; ++ni)
        acc[mi][ni] = __builtin_amdgcn_mfma_f32_16x16x32_bf16(af[mi], bfr[ni],
                                                              acc[mi][ni], 0, 0, 0);
    __syncthreads();
  }

  const int crow0 = bm * 128 + wr * 64;
  const int ccol0 = bn * 128 + wc * 64 + ll;
#pragma unroll
  for (int mi = 0; mi < 4; ++mi) {
#pragma unroll
    for (int ni = 0; ni < 4; ++ni) {
      int c = ccol0 + ni * 16;
#pragma unroll
      for (int j = 0; j < 4; ++j) {
        int r = crow0 + mi * 16 + lg * 4 + j;
        if (FP32OUT) {
          ((float*)Cv)[(size_t)r * ldC + c] = acc[mi][ni][j] + bias[c];
        } else {
          ((u16*)Cv)[(size_t)r * ldC + c] = f2bf(acc[mi][ni][j]);
        }
      }
    }
  }
}

// ------- flash attention (causal): 8-wave, QBLK=256, 32x32 MFMA -----------
// (unchanged from R9 — verified)

__global__ __launch_bounds__(512, 2) void attn(const u16* __restrict__ QK,
                                               const u16* __restrict__ Vt,
                                               u16* __restrict__ AO) {
  __shared__ u16 Klds[4][4096];      // ring of [key 0..63][e 0..63], swizzled
  __shared__ u16 Vlds[4][4096];      // ring of V^T [e][key-slot], swizzled

  const int wg = blockIdx.x;                 // 0..255
  const int lin = (wg & 7) * 32 + (wg >> 3);
  const int bh = lin >> 2, pr = lin & 3;
  const int b = bh >> 4, h = bh & 15;
  const int tid = threadIdx.x;
  const int lane = tid & 63, wv = tid >> 6;  // 8 waves
  const int lq = lane & 31, hi = lane >> 5;

  const int srow = tid >> 3;                 // 0..63
  const int scolb = ((tid & 7) * 16) ^ SWZ(srow);
  const char* ksrc = (const char*)(QK + (size_t)(b * S_ + srow) * 2048 + 1024 + h * E_) + scolb;
  const char* vsrc = (const char*)(Vt + (size_t)(bh * 64 + srow) * 2048) + scolb;

  const int nktA = 4 * pr + 4;
  const int NS = 36;

  auto stage = [&](int sq, int kb) {
    char* kd = (char*)&Klds[0][0] + (sq & 3) * 8192 + wv * 1024;
    char* vd = (char*)&Vlds[0][0] + (sq & 3) * 8192 + wv * 1024;
    __builtin_amdgcn_global_load_lds((const AS1 void*)(ksrc + (size_t)kb * 4096),
                                     (AS3 void*)kd, 16, 0, 0);
    __builtin_amdgcn_global_load_lds((const AS1 void*)(vsrc + kb * 2),
                                     (AS3 void*)vd, 16, 0, 0);
  };

  stage(0, 0);
  stage(1, (1 < nktA ? 1 : 1 - nktA) * 64);

  int seq = 0;
  for (int ph = 0; ph < 2; ++ph) {
    const int qt = ph ? 7 - pr : pr;
    const int nkt = 4 * qt + 4;
    const int qw0 = qt * 256 + wv * 32;
    const int q = qw0 + lq;

    const u16* qp = QK + (size_t)(b * S_ + q) * 2048 + h * E_;
    bf16x8 qf[4];
#pragma unroll
    for (int c = 0; c < 4; ++c)
      qf[c] = *(const bf16x8*)(qp + c * 16 + hi * 8);

    float m_run = -INFINITY, l_part = 0.f;
    f32x16 o0 = {}, o1 = {};

    for (int kt = 0; kt < nkt; ++kt, ++seq) {
      if (seq + 2 < NS) {
        int s2 = seq + 2;
        stage(s2, (s2 < nktA ? s2 : s2 - nktA) * 64);
      }
      if (seq < NS - 2)       asm volatile("s_waitcnt vmcnt(4)" ::: "memory");
      else if (seq == NS - 2) asm volatile("s_waitcnt vmcnt(2)" ::: "memory");
      else                    asm volatile("s_waitcnt vmcnt(0)" ::: "memory");
      __builtin_amdgcn_s_barrier();

      const int kb = kt * 64;
      if (kb > qw0 + 31) continue;         // fully masked for this wave
      const char* kbuf = (const char*)&Klds[0][0] + (seq & 3) * 8192;
      const char* vbuf = (const char*)&Vlds[0][0] + (seq & 3) * 8192;

      auto half = [&](int kb2) __attribute__((always_inline)) {
        f32x16 sc = {};
        __builtin_amdgcn_s_setprio(1);
        const int krow = kb2 * 32 + lq;
#pragma unroll
        for (int c = 0; c < 4; ++c) {
          bf16x8 kf = *(const bf16x8*)(kbuf + krow * 128 +
                                       ((c * 32 + hi * 16) ^ SWZ(krow)));
          sc = __builtin_amdgcn_mfma_f32_32x32x16_bf16(kf, qf[c], sc, 0, 0, 0);
        }
        __builtin_amdgcn_s_setprio(0);

        if (kb + kb2 * 32 + 31 > qw0) {
#pragma unroll
          for (int r = 0; r < 16; ++r) {
            int key = kb + kb2 * 32 + (r & 3) + 8 * (r >> 2) + 4 * hi;
            if (key > q) sc[r] = -1e30f;
          }
        }

        float pm = sc[0];
#pragma unroll
        for (int r = 1; r < 16; ++r) pm = fmaxf(pm, sc[r]);
        if (__any(pm - m_run > 8.0f)) {
          float g = fmaxf(pm, __shfl_xor(pm, 32, 64));
          float mn = fmaxf(m_run, g);
          float corr = exp2f(m_run - mn);
          m_run = mn;
          l_part *= corr;
          o0 *= corr;
          o1 *= corr;
        }

        float p[16];
#pragma unroll
        for (int r = 0; r < 16; ++r) {
          p[r] = exp2f(sc[r] - m_run);
          l_part += p[r];
        }
        __builtin_amdgcn_s_setprio(1);
#pragma unroll
        for (int gg = 0; gg < 2; ++gg) {
          union { unsigned w[4]; bf16x8 v; } pf;
          pf.w[0] = pk2(p[gg * 8 + 0], p[gg * 8 + 1]);
          pf.w[1] = pk2(p[gg * 8 + 2], p[gg * 8 + 3]);
          pf.w[2] = pk2(p[gg * 8 + 4], p[gg * 8 + 5]);
          pf.w[3] = pk2(p[gg * 8 + 6], p[gg * 8 + 7]);
          const int g = kb2 * 2 + gg;
          {
            bf16x8 vf = *(const bf16x8*)(vbuf + lq * 128 +
                                         ((g * 32 + hi * 16) ^ SWZ(lq)));
            o0 = __builtin_amdgcn_mfma_f32_32x32x16_bf16(vf, pf.v, o0, 0, 0, 0);
          }
          {
            const int er = 32 + lq;
            bf16x8 vf = *(const bf16x8*)(vbuf + er * 128 +
                                         ((g * 32 + hi * 16) ^ SWZ(er)));
            o1 = __builtin_amdgcn_mfma_f32_32x32x16_bf16(vf, pf.v, o1, 0, 0, 0);
          }
        }
        __builtin_amdgcn_s_setprio(0);
      };

      half(0);
      if (kb + 32 <= qw0 + 31) half(1);
    }

    float l = l_part + __shfl_xor(l_part, 32, 64);
    float rl = 1.0f / l;

#pragma unroll
    for (int qd = 0; qd < 4; ++qd) {
      u16x4 w0, w1;
#pragma unroll
      for (int j = 0; j < 4; ++j) {
        w0[j] = f2bf(o0[qd * 4 + j] * rl);
        w1[j] = f2bf(o1[qd * 4 + j] * rl);
      }
      const size_t base = (size_t)(b * S_ + q) * D_ + h * E_ + 8 * qd + 4 * hi;
      *(u16x4*)&AO[base] = w0;
      *(u16x4*)&AO[base + 32] = w1;
    }
  }
}

// ---------------- launcher ----------------

extern "C" void kernel_launch(void* const* d_in, const int* in_sizes, int n_in,
                              void* d_out, int out_size, void* d_ws, size_t ws_size,
                              hipStream_t stream) {
  const float* embedded = (const float*)d_in[0];
  const float* Wq = (const float*)d_in[1];
  const float* Wk = (const float*)d_in[2];
  const float* Wv = (const float*)d_in[3];
  const float* Wo = (const float*)d_in[4];
  const float* bo = (const float*)d_in[5];
  float* out = (float*)d_out;

  char* ws = (char*)d_ws;
  u16* X    = (u16*)(ws);                     // [8192][1024]  16 MiB @ 0
  u16* Wqkv = (u16*)(ws + (16u << 20));       // [3072][1024]   6 MiB @ 16M
  u16* WoT  = (u16*)(ws + (22u << 20));       // [1024][1024]   2 MiB @ 22M
  u16* QK   = (u16*)(ws + (24u << 20));       // [8192][2048]  32 MiB @ 24M
  u16* Vt   = (u16*)(ws + (56u << 20));       // [64][64][2048] 16 MiB @ 56M
  u16* AO   = (u16*)(ws + (72u << 20));       // [8192][1024]  16 MiB @ 72M

  // 1) embedded fp32 -> bf16
  cvt4<<<8192, 256, 0, stream>>>(embedded, X, 2097152);
  // 2) W_qkv repack+cast (LDS-transpose, coalesced both sides)
  cvt_wqkv<<<256, 256, 0, stream>>>(Wq, Wk, Wv, Wqkv);
  // 3) Wo cast
  cvt4<<<1024, 256, 0, stream>>>(Wo, WoT, 262144);
  // 4) QKV projection: deep-pipelined 256x192 (Q pre-scaled, V -> sigma Vt)
  gemm_qkv<<<dim3(32, 16), 512, 0, stream>>>(X, Wqkv, QK, Vt);
  // 5) causal flash attention (8-wave, 32x32, counted-vmcnt ring)
  attn<<<256, 512, 0, stream>>>(QK, Vt, AO);
  // 6) output projection + bias -> fp32 d_out
  gemm_bt<true><<<dim3(64, 8), 256, 0, stream>>>(AO, WoT, out, 1024, nullptr,
                                                 bo, M_, 1024, 1024);
}